// Round 1
// baseline (862.382 us; speedup 1.0000x reference)
//
#include <hip/hip_runtime.h>

typedef __bf16 bf16x8 __attribute__((ext_vector_type(8)));
typedef float  f4     __attribute__((ext_vector_type(4)));
typedef unsigned short u16;
typedef unsigned short u16x4 __attribute__((ext_vector_type(4)));
typedef unsigned short u16x8 __attribute__((ext_vector_type(8)));

#define DEV __device__ __forceinline__

DEV u16 f2bf(float x) {                 // round-to-nearest-even fp32 -> bf16
  unsigned u = __float_as_uint(x);
  unsigned r = u + 0x7FFFu + ((u >> 16) & 1u);
  return (u16)(r >> 16);
}
DEV float bf2f(u16 h) { return __uint_as_float(((unsigned)h) << 16); }

typedef const __attribute__((address_space(1))) void gv_t;
typedef __attribute__((address_space(3))) void lv_t;
DEV void g2l16(const void* g, void* l) {
  __builtin_amdgcn_global_load_lds((gv_t*)g, (lv_t*)l, 16, 0, 0);
}

// ---------------------------------------------------------------------------
// prep: fp32 -> bf16 hi/lo split (elementwise), for A operands
__global__ void split_kernel(const float* __restrict__ src,
                             u16* __restrict__ hi, u16* __restrict__ lo) {
  size_t i = (size_t)blockIdx.x * 256 + threadIdx.x;   // float4 index
  float4 v = ((const float4*)src)[i];
  u16x4 h, l;
  u16 a;
  a = f2bf(v.x); h[0] = a; l[0] = f2bf(v.x - bf2f(a));
  a = f2bf(v.y); h[1] = a; l[1] = f2bf(v.y - bf2f(a));
  a = f2bf(v.z); h[2] = a; l[2] = f2bf(v.z - bf2f(a));
  a = f2bf(v.w); h[3] = a; l[3] = f2bf(v.w - bf2f(a));
  ((u16x4*)hi)[i] = h; ((u16x4*)lo)[i] = l;
}

// prep: W [1024][J] fp32 -> transposed hi/lo bf16 [J][1024] (B^T form for GEMM)
__global__ void wsplit_t_kernel(const float* __restrict__ W,
                                u16* __restrict__ th, u16* __restrict__ tl, int J) {
  int j0 = blockIdx.x * 64, k0 = blockIdx.y * 64;
  __shared__ float tile[64][68];
  int t = threadIdx.x;
  int r16 = t >> 4, q = t & 15;
#pragma unroll
  for (int p = 0; p < 4; ++p) {
    int kk = r16 + p * 16;
    float4 v = *(const float4*)(W + (size_t)(k0 + kk) * J + j0 + q * 4);
    tile[kk][q * 4 + 0] = v.x; tile[kk][q * 4 + 1] = v.y;
    tile[kk][q * 4 + 2] = v.z; tile[kk][q * 4 + 3] = v.w;
  }
  __syncthreads();
  int rr = t >> 2, cq = t & 3;
  u16x8 h0, h1, l0, l1;
#pragma unroll
  for (int i = 0; i < 8; ++i) {
    float v = tile[cq * 16 + i][rr];
    u16 hh = f2bf(v); h0[i] = hh; l0[i] = f2bf(v - bf2f(hh));
    float v2 = tile[cq * 16 + 8 + i][rr];
    u16 hb = f2bf(v2); h1[i] = hb; l1[i] = f2bf(v2 - bf2f(hb));
  }
  size_t ob = (size_t)(j0 + rr) * 1024 + k0 + cq * 16;
  *(u16x8*)(th + ob) = h0; *(u16x8*)(th + ob + 8) = h1;
  *(u16x8*)(tl + ob) = l0; *(u16x8*)(tl + ob + 8) = l1;
}

// ---------------------------------------------------------------------------
// split-precision GEMM: C = (Ahi+Alo) @ (Bhi+Blo)^T  (3 products, K=1024)
// EPI 0: QKV -> bf16 qkvs [4096][3072], q-part scaled 1/8, +bias(bq|bk|bv)
// EPI 1: x = C + bo + h   (fp32 [4096][1024])
// EPI 2: g = C + b1       (fp32 [4096][512])
template <int EPI>
__global__ __launch_bounds__(256, 2) void gemm_split_kernel(
    const u16* __restrict__ Ahi, const u16* __restrict__ Alo,
    const u16* __restrict__ Bthi, const u16* __restrict__ Btlo,
    float* __restrict__ Cf, u16* __restrict__ Cbf,
    const float* __restrict__ bias0, const float* __restrict__ bias1,
    const float* __restrict__ bias2, const float* __restrict__ Hres) {
  __shared__ alignas(16) u16 a_lds[2][4096];
  __shared__ alignas(16) u16 b_lds[2][4096];
  int t = threadIdx.x, l = t & 63, w = t >> 6;
  int wr = w >> 1, wc = w & 1, lr = l & 15, g = l >> 4;
  int m0 = blockIdx.y * 128, n0 = blockIdx.x * 128;

  f4 acc[4][4];
#pragma unroll
  for (int i = 0; i < 4; ++i)
#pragma unroll
    for (int j = 0; j < 4; ++j) acc[i][j] = (f4){0.f, 0.f, 0.f, 0.f};

  auto stage = [&](int s, int buf) {
    int p = s >> 5, k0 = (s & 31) * 32;
    const u16* As = (p < 2) ? Ahi : Alo;
    const u16* Bs = (p == 1) ? Btlo : Bthi;
#pragma unroll
    for (int i = 0; i < 2; ++i) {
      int idx = t + i * 256, r = idx >> 2, c = idx & 3;
      g2l16(As + (size_t)(m0 + r) * 1024 + k0 + 8 * (c ^ (r & 3)), &a_lds[buf][idx * 8]);
    }
#pragma unroll
    for (int i = 0; i < 2; ++i) {
      int idx = t + i * 256, r = idx >> 2, c = idx & 3;
      g2l16(Bs + (size_t)(n0 + r) * 1024 + k0 + 8 * (c ^ (r & 3)), &b_lds[buf][idx * 8]);
    }
  };

  stage(0, 0);
  for (int s = 0; s < 96; ++s) {
    __syncthreads();                       // drains vmcnt: buf[s&1] ready
    if (s + 1 < 96) stage(s + 1, (s + 1) & 1);
    const u16* ab = a_lds[s & 1];
    const u16* bb = b_lds[s & 1];
    bf16x8 af[4], bf[4];
#pragma unroll
    for (int mt = 0; mt < 4; ++mt) {
      int row = wr * 64 + mt * 16 + lr;
      af[mt] = *(const bf16x8*)(ab + row * 32 + 8 * (g ^ (row & 3)));
    }
#pragma unroll
    for (int nt = 0; nt < 4; ++nt) {
      int row = wc * 64 + nt * 16 + lr;
      bf[nt] = *(const bf16x8*)(bb + row * 32 + 8 * (g ^ (row & 3)));
    }
#pragma unroll
    for (int mt = 0; mt < 4; ++mt)
#pragma unroll
      for (int nt = 0; nt < 4; ++nt)
        acc[mt][nt] = __builtin_amdgcn_mfma_f32_16x16x32_bf16(af[mt], bf[nt], acc[mt][nt], 0, 0, 0);
  }

#pragma unroll
  for (int mt = 0; mt < 4; ++mt)
#pragma unroll
    for (int nt = 0; nt < 4; ++nt) {
      int col = n0 + wc * 64 + nt * 16 + lr;
#pragma unroll
      for (int r = 0; r < 4; ++r) {
        int row = m0 + wr * 64 + mt * 16 + 4 * g + r;
        float v = acc[mt][nt][r];
        if (EPI == 0) {
          float b = (col < 1024) ? bias0[col] : (col < 2048 ? bias1[col - 1024] : bias2[col - 2048]);
          v += b;
          if (col < 1024) v *= 0.125f;     // fold 1/sqrt(HD) into q
          Cbf[(size_t)row * 3072 + col] = f2bf(v);
        } else if (EPI == 1) {
          v += bias0[col] + Hres[(size_t)row * 1024 + col];
          Cf[(size_t)row * 1024 + col] = v;
        } else {
          v += bias0[col];
          Cf[(size_t)row * 512 + col] = v;
        }
      }
    }
}

// ---------------------------------------------------------------------------
// retile K,V for attention fragment streaming:
// kt [mblk=256][cc=128][m=16][8]  (K rows, d-contiguous per fragment)
// vt2[mblk=256][row=1024][m=16]   (V^T, m-contiguous per fragment)
__global__ void kv_retile_kernel(const u16* __restrict__ qkvs,
                                 u16* __restrict__ kt, u16* __restrict__ vt2) {
  int mblk = blockIdx.x, t = threadIdx.x;
  __shared__ alignas(16) u16 lds[16][1032];
#pragma unroll
  for (int p = 0; p < 8; ++p) {
    int idx = t + p * 256, r = idx >> 7, c8 = idx & 127;
    *(u16x8*)(&lds[r][c8 * 8]) =
        *(const u16x8*)(qkvs + (size_t)(mblk * 16 + r) * 3072 + 1024 + c8 * 8);
  }
  __syncthreads();
#pragma unroll
  for (int p = 0; p < 8; ++p) {
    int ch = t + p * 256, cc = ch >> 4, m = ch & 15;
    u16x8 v = *(const u16x8*)(&lds[m][cc * 8]);
    *(u16x8*)(kt + (size_t)mblk * 16384 + cc * 128 + m * 8) = v;
  }
  __syncthreads();
#pragma unroll
  for (int p = 0; p < 8; ++p) {
    int idx = t + p * 256, r = idx >> 7, c8 = idx & 127;
    *(u16x8*)(&lds[r][c8 * 8]) =
        *(const u16x8*)(qkvs + (size_t)(mblk * 16 + r) * 3072 + 2048 + c8 * 8);
  }
  __syncthreads();
#pragma unroll
  for (int p = 0; p < 8; ++p) {
    int ch = t + p * 256, row = ch >> 1, half = ch & 1;
    u16x8 v;
#pragma unroll
    for (int i = 0; i < 8; ++i) v[i] = lds[half * 8 + i][row];
    *(u16x8*)(vt2 + (size_t)mblk * 16384 + row * 16 + half * 8) = v;
  }
}

// ---------------------------------------------------------------------------
// attention: softmax over HEADS per (n,m); out^T partials per m-half.
// block = 8 waves: nsub = w>>2 (16 q-rows each), grp = w&3 (4 heads each)
__global__ __launch_bounds__(512, 2) void attn_kernel(
    const u16* __restrict__ qkvs, const u16* __restrict__ kt,
    const u16* __restrict__ vt2, float* __restrict__ out_part) {
  int t = threadIdx.x, l = t & 63, w = t >> 6;
  int nsub = w >> 2, grp = w & 3, lr = l & 15, g = l >> 4;
  int b = blockIdx.x, n0 = (b >> 1) * 32, mhalf = b & 1;
  int nrow = n0 + nsub * 16 + lr;

  __shared__ float zbuf[2][4][16][16];

  // hoisted Q fragments (B-operand of swapped QK^T): [head][kstep]
  bf16x8 qf[4][2];
#pragma unroll
  for (int hh = 0; hh < 4; ++hh)
#pragma unroll
    for (int ks = 0; ks < 2; ++ks)
      qf[hh][ks] = *(const bf16x8*)(qkvs + (size_t)nrow * 3072 + (grp * 4 + hh) * 64 + ks * 32 + 8 * g);

  f4 oacc[4][4];
#pragma unroll
  for (int i = 0; i < 4; ++i)
#pragma unroll
    for (int j = 0; j < 4; ++j) oacc[i][j] = (f4){0.f, 0.f, 0.f, 0.f};

  float* opb = out_part + (size_t)mhalf * 1024 * 4096;

  for (int step = 0; step < 128; ++step) {
    int mblk = mhalf * 128 + step;
    const u16* ktb = kt + (size_t)mblk * 16384;
    const u16* vtb = vt2 + (size_t)mblk * 16384;

    // prefetch V^T fragments for this step (consumed after the barrier;
    // raw s_barrier below does NOT drain vmcnt, so these stay in flight)
    u16x4 va[4][4];
#pragma unroll
    for (int hh = 0; hh < 4; ++hh)
#pragma unroll
      for (int dc = 0; dc < 4; ++dc) {
        int vrow = (grp * 4 + hh) * 64 + dc * 16 + lr;
        va[hh][dc] = *(const u16x4*)(vtb + vrow * 16 + 4 * g);
      }

    // S^T = K_tile @ Q^T  per head (C-frag: row=m=4g+r, col=n=lr)
    f4 sacc[4];
#pragma unroll
    for (int hh = 0; hh < 4; ++hh) sacc[hh] = (f4){0.f, 0.f, 0.f, 0.f};
#pragma unroll
    for (int ks = 0; ks < 2; ++ks) {
      bf16x8 kf[4];
#pragma unroll
      for (int hh = 0; hh < 4; ++hh) {
        int cc = (grp * 4 + hh) * 8 + ks * 4 + g;
        kf[hh] = *(const bf16x8*)(ktb + (cc * 16 + lr) * 8);
      }
#pragma unroll
      for (int hh = 0; hh < 4; ++hh)
        sacc[hh] = __builtin_amdgcn_mfma_f32_16x16x32_bf16(kf[hh], qf[hh][ks], sacc[hh], 0, 0, 0);
    }

    float ep[4][4], zp[4] = {0.f, 0.f, 0.f, 0.f};
#pragma unroll
    for (int hh = 0; hh < 4; ++hh)
#pragma unroll
      for (int r = 0; r < 4; ++r) {
        float e = __expf(sacc[hh][r]);
        ep[hh][r] = e; zp[r] += e;
      }
#pragma unroll
    for (int r = 0; r < 4; ++r) zbuf[nsub][grp][4 * g + r][lr] = zp[r];

    asm volatile("s_waitcnt lgkmcnt(0)" ::: "memory");
    __builtin_amdgcn_sched_barrier(0);
    __builtin_amdgcn_s_barrier();

    float invz[4];
#pragma unroll
    for (int r = 0; r < 4; ++r) {
      float z = zbuf[nsub][0][4 * g + r][lr] + zbuf[nsub][1][4 * g + r][lr] +
                zbuf[nsub][2][4 * g + r][lr] + zbuf[nsub][3][4 * g + r][lr];
      invz[r] = 1.0f / z;
    }

    // PV: out^T += V^T @ attn^T ; attn^T frag is lane-local (swapped trick)
#pragma unroll
    for (int hh = 0; hh < 4; ++hh) {
      u16x8 pbu = (u16x8){0, 0, 0, 0, 0, 0, 0, 0};
      pbu[0] = f2bf(ep[hh][0] * invz[0]);
      pbu[1] = f2bf(ep[hh][1] * invz[1]);
      pbu[2] = f2bf(ep[hh][2] * invz[2]);
      pbu[3] = f2bf(ep[hh][3] * invz[3]);
      bf16x8 pb = __builtin_bit_cast(bf16x8, pbu);
#pragma unroll
      for (int dc = 0; dc < 4; ++dc) {
        u16x8 au = (u16x8){0, 0, 0, 0, 0, 0, 0, 0};
        au[0] = va[hh][dc][0]; au[1] = va[hh][dc][1];
        au[2] = va[hh][dc][2]; au[3] = va[hh][dc][3];
        bf16x8 af = __builtin_bit_cast(bf16x8, au);
        oacc[hh][dc] = __builtin_amdgcn_mfma_f32_16x16x32_bf16(af, pb, oacc[hh][dc], 0, 0, 0);
      }
    }
    asm volatile("s_waitcnt lgkmcnt(0)" ::: "memory");
    __builtin_amdgcn_sched_barrier(0);
    __builtin_amdgcn_s_barrier();          // zbuf reuse guard
  }

#pragma unroll
  for (int hh = 0; hh < 4; ++hh)
#pragma unroll
    for (int dc = 0; dc < 4; ++dc)
#pragma unroll
      for (int r = 0; r < 4; ++r) {
        int c = (grp * 4 + hh) * 64 + dc * 16 + 4 * g + r;
        opb[(size_t)c * 4096 + nrow] = oacc[hh][dc][r];
      }
}

// ---------------------------------------------------------------------------
// combine m-half partials: [2][1024][4096] -> ao hi/lo bf16 [4096][1024]
__global__ void combine_kernel(const float* __restrict__ part,
                               u16* __restrict__ aoh, u16* __restrict__ aol) {
  int n0 = blockIdx.x * 64, c0 = blockIdx.y * 64;
  __shared__ float tl[64][68];
  int t = threadIdx.x;
  int r16 = t >> 4, q = t & 15;
#pragma unroll
  for (int p = 0; p < 4; ++p) {
    int cc = r16 + p * 16;
    size_t off = (size_t)(c0 + cc) * 4096 + n0 + q * 4;
    float4 v0 = *(const float4*)(part + off);
    float4 v1 = *(const float4*)(part + 4194304u + off);
    tl[cc][q * 4 + 0] = v0.x + v1.x;
    tl[cc][q * 4 + 1] = v0.y + v1.y;
    tl[cc][q * 4 + 2] = v0.z + v1.z;
    tl[cc][q * 4 + 3] = v0.w + v1.w;
  }
  __syncthreads();
  int rr = t >> 2, cq = t & 3;
  u16x8 h0, h1, l0, l1;
#pragma unroll
  for (int i = 0; i < 8; ++i) {
    float v = tl[cq * 16 + i][rr];
    u16 hh = f2bf(v); h0[i] = hh; l0[i] = f2bf(v - bf2f(hh));
    float v2 = tl[cq * 16 + 8 + i][rr];
    u16 hb = f2bf(v2); h1[i] = hb; l1[i] = f2bf(v2 - bf2f(hb));
  }
  size_t ob = (size_t)(n0 + rr) * 1024 + c0 + cq * 16;
  *(u16x8*)(aoh + ob) = h0; *(u16x8*)(aoh + ob + 8) = h1;
  *(u16x8*)(aol + ob) = l0; *(u16x8*)(aol + ob + 8) = l1;
}

// ---------------------------------------------------------------------------
__global__ __launch_bounds__(256) void ln_kernel(
    const float* __restrict__ x, const float* __restrict__ lnw,
    const float* __restrict__ lnb, float* __restrict__ hn_out,
    u16* __restrict__ hnh, u16* __restrict__ hnl) {
  int row = blockIdx.x, t = threadIdx.x;
  const float* xr = x + (size_t)row * 1024;
  float4 v = *(const float4*)(xr + t * 4);
  float s = v.x + v.y + v.z + v.w;
  float sq = v.x * v.x + v.y * v.y + v.z * v.z + v.w * v.w;
#pragma unroll
  for (int o = 32; o > 0; o >>= 1) { s += __shfl_down(s, o); sq += __shfl_down(sq, o); }
  __shared__ float red[8];
  __shared__ float mv[2];
  if ((t & 63) == 0) { red[t >> 6] = s; red[4 + (t >> 6)] = sq; }
  __syncthreads();
  if (t == 0) {
    float S = red[0] + red[1] + red[2] + red[3];
    float Q = red[4] + red[5] + red[6] + red[7];
    float mu = S * (1.0f / 1024.0f);
    float var = Q * (1.0f / 1024.0f) - mu * mu;
    mv[0] = mu; mv[1] = rsqrtf(var + 1e-5f);
  }
  __syncthreads();
  float mu = mv[0], rstd = mv[1];
  float4 wv = *(const float4*)(lnw + t * 4);
  float4 bv = *(const float4*)(lnb + t * 4);
  float4 o;
  o.x = (v.x - mu) * rstd * wv.x + bv.x;
  o.y = (v.y - mu) * rstd * wv.y + bv.y;
  o.z = (v.z - mu) * rstd * wv.z + bv.z;
  o.w = (v.w - mu) * rstd * wv.w + bv.w;
  *(float4*)(hn_out + (size_t)row * 1024 + t * 4) = o;
  u16x4 hh, ll; u16 a;
  a = f2bf(o.x); hh[0] = a; ll[0] = f2bf(o.x - bf2f(a));
  a = f2bf(o.y); hh[1] = a; ll[1] = f2bf(o.y - bf2f(a));
  a = f2bf(o.z); hh[2] = a; ll[2] = f2bf(o.z - bf2f(a));
  a = f2bf(o.w); hh[3] = a; ll[3] = f2bf(o.w - bf2f(a));
  *(u16x4*)(hnh + (size_t)row * 1024 + t * 4) = hh;
  *(u16x4*)(hnl + (size_t)row * 1024 + t * 4) = ll;
}

__global__ __launch_bounds__(128) void cw_kernel(
    const float* __restrict__ g, const float* __restrict__ W2,
    const float* __restrict__ b2, float* __restrict__ cw) {
  int row = blockIdx.x, t = threadIdx.x;
  float4 v = *(const float4*)(g + (size_t)row * 512 + t * 4);
  float4 wv = *(const float4*)(W2 + t * 4);
  float s = (v.x / (1.0f + __expf(-v.x))) * wv.x + (v.y / (1.0f + __expf(-v.y))) * wv.y +
            (v.z / (1.0f + __expf(-v.z))) * wv.z + (v.w / (1.0f + __expf(-v.w))) * wv.w;
#pragma unroll
  for (int o = 32; o > 0; o >>= 1) s += __shfl_down(s, o);
  __shared__ float red[2];
  if ((t & 63) == 0) red[t >> 6] = s;
  __syncthreads();
  if (t == 0) cw[row] = red[0] + red[1] + b2[0];
}

__global__ __launch_bounds__(256) void rowmean_kernel(
    const float* __restrict__ rel, const float* __restrict__ cw,
    float* __restrict__ pu) {
  int n = blockIdx.x, t = threadIdx.x;
  const float* base = rel + (size_t)n * 12288;
  float a0 = 0.f, a1 = 0.f, a2 = 0.f;
#pragma unroll
  for (int it = 0; it < 12; ++it) {
    int e4 = it * 256 + t;
    float4 v = *(const float4*)(base + (size_t)e4 * 4);
    int rm = e4 % 3;                     // (e4*4) % 3 == e4 % 3
    if (rm == 0)      { a0 += v.x; a1 += v.y; a2 += v.z; a0 += v.w; }
    else if (rm == 1) { a1 += v.x; a2 += v.y; a0 += v.z; a1 += v.w; }
    else              { a2 += v.x; a0 += v.y; a1 += v.z; a2 += v.w; }
  }
#pragma unroll
  for (int o = 32; o > 0; o >>= 1) {
    a0 += __shfl_down(a0, o); a1 += __shfl_down(a1, o); a2 += __shfl_down(a2, o);
  }
  __shared__ float red[4][3];
  if ((t & 63) == 0) { red[t >> 6][0] = a0; red[t >> 6][1] = a1; red[t >> 6][2] = a2; }
  __syncthreads();
  if (t == 0) {
    float s0 = red[0][0] + red[1][0] + red[2][0] + red[3][0];
    float s1 = red[0][1] + red[1][1] + red[2][1] + red[3][1];
    float s2 = red[0][2] + red[1][2] + red[2][2] + red[3][2];
    float c = cw[n] * (1.0f / 4096.0f);
    pu[n * 3 + 0] = c * s0; pu[n * 3 + 1] = c * s1; pu[n * 3 + 2] = c * s2;
  }
}

// ---------------------------------------------------------------------------
extern "C" void kernel_launch(void* const* d_in, const int* in_sizes, int n_in,
                              void* d_out, int out_size, void* d_ws, size_t ws_size,
                              hipStream_t stream) {
  const float* h   = (const float*)d_in[0];
  const float* rel = (const float*)d_in[1];
  const float* Wq  = (const float*)d_in[2];
  const float* bq  = (const float*)d_in[3];
  const float* Wk  = (const float*)d_in[4];
  const float* bk  = (const float*)d_in[5];
  const float* Wv  = (const float*)d_in[6];
  const float* bv  = (const float*)d_in[7];
  const float* Wo  = (const float*)d_in[8];
  const float* bo  = (const float*)d_in[9];
  const float* W1  = (const float*)d_in[10];
  const float* b1  = (const float*)d_in[11];
  const float* W2  = (const float*)d_in[12];
  const float* b2  = (const float*)d_in[13];
  const float* lnw = (const float*)d_in[14];
  const float* lnb = (const float*)d_in[15];
  float* out_hn = (float*)d_out;
  float* out_pu = (float*)d_out + 4194304;

  char* ws = (char*)d_ws;
  u16*   wqkv_th = (u16*)(ws);                    // [3072][1024]
  u16*   wqkv_tl = (u16*)(ws + 6291456);
  u16*   wo_th   = (u16*)(ws + 12582912);         // [1024][1024]
  u16*   wo_tl   = (u16*)(ws + 14680064);
  u16*   w1_th   = (u16*)(ws + 16777216);         // [512][1024]
  u16*   w1_tl   = (u16*)(ws + 17825792);
  u16*   h_hi    = (u16*)(ws + 18874368);         // later reused as hn_hi
  u16*   h_lo    = (u16*)(ws + 27262976);         // later reused as hn_lo
  u16*   qkvs    = (u16*)(ws + 35651584);         // [4096][3072] bf16 (q scaled)
  u16*   ao_hi   = (u16*)(ws + 35651584);         // alias: qkvs dead after attn
  u16*   ao_lo   = (u16*)(ws + 44040192);
  u16*   kt      = (u16*)(ws + 60817408);         // [256][128][16][8]
  u16*   vt2     = (u16*)(ws + 69206016);         // [256][1024][16]
  float* opart   = (float*)(ws + 77594624);       // [2][1024][4096]
  float* xbuf    = (float*)(ws + 77594624);       // alias: opart dead after combine
  float* gbuf    = (float*)(ws + 94371840);       // [4096][512]
  float* cw      = (float*)(ws + 111149056);      // [4096]

  // prep: splits + weight transposes
  split_kernel<<<4096, 256, 0, stream>>>(h, h_hi, h_lo);
  wsplit_t_kernel<<<dim3(16, 16), 256, 0, stream>>>(Wq, wqkv_th, wqkv_tl, 1024);
  wsplit_t_kernel<<<dim3(16, 16), 256, 0, stream>>>(Wk, wqkv_th + 1048576, wqkv_tl + 1048576, 1024);
  wsplit_t_kernel<<<dim3(16, 16), 256, 0, stream>>>(Wv, wqkv_th + 2097152, wqkv_tl + 2097152, 1024);
  wsplit_t_kernel<<<dim3(16, 16), 256, 0, stream>>>(Wo, wo_th, wo_tl, 1024);
  wsplit_t_kernel<<<dim3(8, 16), 256, 0, stream>>>(W1, w1_th, w1_tl, 512);

  // QKV projection (split-precision), writes bf16 q(scaled)|k|v
  gemm_split_kernel<0><<<dim3(24, 32), 256, 0, stream>>>(
      h_hi, h_lo, wqkv_th, wqkv_tl, nullptr, qkvs, bq, bk, bv, nullptr);

  kv_retile_kernel<<<256, 256, 0, stream>>>(qkvs, kt, vt2);

  attn_kernel<<<256, 512, 0, stream>>>(qkvs, kt, vt2, opart);

  combine_kernel<<<dim3(64, 16), 256, 0, stream>>>(opart, ao_hi, ao_lo);

  // x = ao @ Wo + bo + h
  gemm_split_kernel<1><<<dim3(8, 32), 256, 0, stream>>>(
      ao_hi, ao_lo, wo_th, wo_tl, xbuf, nullptr, bo, nullptr, nullptr, h);

  ln_kernel<<<4096, 256, 0, stream>>>(xbuf, lnw, lnb, out_hn, h_hi, h_lo);

  // g = hn @ W1 + b1
  gemm_split_kernel<2><<<dim3(4, 32), 256, 0, stream>>>(
      h_hi, h_lo, w1_th, w1_tl, gbuf, nullptr, b1, nullptr, nullptr, nullptr);

  cw_kernel<<<4096, 128, 0, stream>>>(gbuf, W2, b2, cw);

  rowmean_kernel<<<4096, 256, 0, stream>>>(rel, cw, out_pu);
}